// Round 4
// baseline (846.241 us; speedup 1.0000x reference)
//
#include <hip/hip_runtime.h>
#include <hip/hip_cooperative_groups.h>
#include <cstddef>
#include <cstdint>

namespace cg = cooperative_groups;

#define H 128
#define EDIM 16
#define NLAYER 3
#define NSLICE 18            // 16 edge_W slices + edge_b + root_W
#define WCOLS (NSLICE * H)   // 2304
#define PCOLS (EDIM * H)     // 2048 bf16 cols of P
#define NBLK 512             // cooperative grid size (2 blocks/CU)
#define NTHR 256

typedef unsigned short ushort_t;
typedef unsigned int uint_t;
typedef __attribute__((ext_vector_type(8))) short bf16x8;
typedef __attribute__((ext_vector_type(4))) float f32x4;

__device__ __forceinline__ ushort_t f2bf(float f) {
    uint_t u = __builtin_bit_cast(uint_t, f);
    u += 0x7fffu + ((u >> 16) & 1u);   // RNE
    return (ushort_t)(u >> 16);
}
__device__ __forceinline__ float bf_lo(uint_t u) {
    return __builtin_bit_cast(float, u << 16);
}
__device__ __forceinline__ float bf_hi(uint_t u) {
    return __builtin_bit_cast(float, u & 0xffff0000u);
}

struct MP {
    const float *x, *eattr, *node_W, *node_b, *edge_W, *edge_b, *root_W;
    const float *conv_b, *gamma, *beta, *W1, *b1, *W2, *b2;
    const int *src, *dst, *batch;
    int *hist, *fill, *offs, *eord;
    float *cntG, *bnS, *bnQ, *gsum, *h, *xnew, *QR, *out;
    ushort_t *hbf, *Wt, *Pb;
    int E, N, G;
};

// ---- weight prep: fp32 [k][o] slice -> bf16 Wt[l][n][k] (blocks 0..53) ----
__device__ __forceinline__ void wprep_phase(const MP& p, unsigned char* smem)
{
    ushort_t* tile = (ushort_t*)smem;          // [128][136]
    const int b = blockIdx.x;                   // 0..53
    const int l = b / NSLICE, s = b % NSLICE;
    const float* S = (s < 16) ? (p.edge_W + ((size_t)l * 16 + s) * (H * H))
                   : (s == 16 ? (p.edge_b + (size_t)l * H * H)
                              : (p.root_W + (size_t)l * H * H));
    const int t = threadIdx.x;
    const int k = t >> 1, o0 = (t & 1) * 64;
#pragma unroll
    for (int j = 0; j < 64; j += 4) {
        float4 v = *(const float4*)&S[(size_t)k * H + o0 + j];
        tile[k * 136 + o0 + j + 0] = f2bf(v.x);
        tile[k * 136 + o0 + j + 1] = f2bf(v.y);
        tile[k * 136 + o0 + j + 2] = f2bf(v.z);
        tile[k * 136 + o0 + j + 3] = f2bf(v.w);
    }
    __syncthreads();
    const int n = t >> 1, k0 = (t & 1) * 64;
    ushort_t* outp = p.Wt + ((size_t)l * WCOLS + s * H + n) * H + k0;
#pragma unroll 8
    for (int j = 0; j < 64; ++j) outp[j] = tile[(k0 + j) * 136 + n];
}

// ---- node embed: h = x @ node_W + node_b (fp32, K=32); blocks 54..117 ----
__device__ __forceinline__ void embed_phase(const MP& p, unsigned char* smem)
{
    float* As = (float*)smem;                  // [16][68]
    float* Bs = As + 16 * 68;                  // [16][68]
    const int tt = blockIdx.x - 54;            // 0..63
    const int bm = (tt >> 1) * 64;
    const int bn = (tt & 1) * 64;
    const int tid = threadIdx.x;
    const int tx = tid & 15, ty = tid >> 4;

    float acc[4][4];
#pragma unroll
    for (int i = 0; i < 4; ++i)
#pragma unroll
        for (int j = 0; j < 4; ++j) acc[i][j] = 0.f;

    const int ka = tid & 15, ma = tid >> 4;
    const int nb = tid & 63, kb = tid >> 6;

    for (int k0 = 0; k0 < 32; k0 += 16) {
#pragma unroll
        for (int r = 0; r < 4; ++r)
            As[ka * 68 + ma + 16 * r] = p.x[(size_t)(bm + ma + 16 * r) * 32 + (k0 + ka)];
#pragma unroll
        for (int r = 0; r < 4; ++r)
            Bs[(kb + 4 * r) * 68 + nb] = p.node_W[(size_t)(k0 + kb + 4 * r) * H + bn + nb];
        __syncthreads();
#pragma unroll
        for (int kk = 0; kk < 16; ++kk) {
            const float4 a4 = *(const float4*)&As[kk * 68 + ty * 4];
            const float4 b4 = *(const float4*)&Bs[kk * 68 + tx * 4];
            const float a[4] = {a4.x, a4.y, a4.z, a4.w};
            const float bb[4] = {b4.x, b4.y, b4.z, b4.w};
#pragma unroll
            for (int i = 0; i < 4; ++i)
#pragma unroll
                for (int j = 0; j < 4; ++j)
                    acc[i][j] = fmaf(a[i], bb[j], acc[i][j]);
        }
        __syncthreads();
    }
#pragma unroll
    for (int i = 0; i < 4; ++i) {
        const int row = bm + ty * 4 + i;
        float4 v;
        v.x = acc[i][0] + p.node_b[bn + tx * 4 + 0];
        v.y = acc[i][1] + p.node_b[bn + tx * 4 + 1];
        v.z = acc[i][2] + p.node_b[bn + tx * 4 + 2];
        v.w = acc[i][3] + p.node_b[bn + tx * 4 + 3];
        *(float4*)&p.h[(size_t)row * H + bn + tx * 4] = v;
        ushort_t* o = &p.hbf[(size_t)row * H + bn + tx * 4];
        o[0] = f2bf(v.x); o[1] = f2bf(v.y); o[2] = f2bf(v.z); o[3] = f2bf(v.w);
    }
}

// ---- exclusive scan of hist -> offs (block 0 only, N=2048) ----------------
__device__ __forceinline__ void scan_phase(const MP& p, unsigned char* smem)
{
    int* part = (int*)smem;
    const int t = threadIdx.x;
    const int base = t * 8;
    int v[8], loc[8], s = 0;
#pragma unroll
    for (int j = 0; j < 8; ++j) v[j] = p.hist[base + j];
#pragma unroll
    for (int j = 0; j < 8; ++j) { loc[j] = s; s += v[j]; }
    part[t] = s;
    __syncthreads();
    for (int off = 1; off < 256; off <<= 1) {
        int x = (t >= off) ? part[t - off] : 0;
        __syncthreads();
        part[t] += x;
        __syncthreads();
    }
    const int boff = (t == 0) ? 0 : part[t - 1];
#pragma unroll
    for (int j = 0; j < 8; ++j) p.offs[base + j] = boff + loc[j];
    if (t == 255) p.offs[p.N] = boff + s;
}

// ---- bf16 MFMA GEMM phase: grid-stride over 1152 64x64 tiles --------------
__device__ __forceinline__ void mfma_phase(const MP& p, int l, unsigned char* smem)
{
    ushort_t* As = (ushort_t*)smem;            // [64][136]
    ushort_t* Bs = As + 64 * 136;              // [64][136]
    const ushort_t* Wt = p.Wt + (size_t)l * WCOLS * H;
    const int tid = threadIdx.x;
    const int ntile = (WCOLS / 64) * (p.N / 64);   // 1152

    for (int t = blockIdx.x; t < ntile; t += NBLK) {
        const int bx = t % (WCOLS / 64);
        const int by = t / (WCOLS / 64);
        const int v0 = by * 64;
        const int n0 = bx * 64;
        {
            const int row = tid >> 2, col0 = (tid & 3) * 32;
            const ushort_t* ga = p.hbf + (size_t)(v0 + row) * H + col0;
            const ushort_t* gb = Wt + (size_t)(n0 + row) * H + col0;
#pragma unroll
            for (int j = 0; j < 32; j += 8) {
                *(uint4*)&As[row * 136 + col0 + j] = *(const uint4*)(ga + j);
                *(uint4*)&Bs[row * 136 + col0 + j] = *(const uint4*)(gb + j);
            }
        }
        __syncthreads();

        const int wave = tid >> 6, lane = tid & 63;
        const int l15 = lane & 15, kg = lane >> 4;
        const int mrow = wave * 16 + l15;

        f32x4 acc0 = {0.f, 0.f, 0.f, 0.f};
        f32x4 acc1 = {0.f, 0.f, 0.f, 0.f};
        f32x4 acc2 = {0.f, 0.f, 0.f, 0.f};
        f32x4 acc3 = {0.f, 0.f, 0.f, 0.f};

#pragma unroll
        for (int s = 0; s < 4; ++s) {
            const int k = s * 32 + kg * 8;
            bf16x8 a  = *(const bf16x8*)&As[mrow * 136 + k];
            bf16x8 b0 = *(const bf16x8*)&Bs[(0 * 16 + l15) * 136 + k];
            bf16x8 b1 = *(const bf16x8*)&Bs[(1 * 16 + l15) * 136 + k];
            bf16x8 b2 = *(const bf16x8*)&Bs[(2 * 16 + l15) * 136 + k];
            bf16x8 b3 = *(const bf16x8*)&Bs[(3 * 16 + l15) * 136 + k];
            acc0 = __builtin_amdgcn_mfma_f32_16x16x32_bf16(a, b0, acc0, 0, 0, 0);
            acc1 = __builtin_amdgcn_mfma_f32_16x16x32_bf16(a, b1, acc1, 0, 0, 0);
            acc2 = __builtin_amdgcn_mfma_f32_16x16x32_bf16(a, b2, acc2, 0, 0, 0);
            acc3 = __builtin_amdgcn_mfma_f32_16x16x32_bf16(a, b3, acc3, 0, 0, 0);
        }

        const int slice = n0 >> 7;
        const int lo = n0 & 127;
        const int row0 = v0 + wave * 16 + kg * 4;
        if (slice < 16) {
            ushort_t* op = p.Pb + (size_t)row0 * PCOLS + slice * H + lo + l15;
#pragma unroll
            for (int r = 0; r < 4; ++r) {
                op[(size_t)r * PCOLS + 0]  = f2bf(acc0[r]);
                op[(size_t)r * PCOLS + 16] = f2bf(acc1[r]);
                op[(size_t)r * PCOLS + 32] = f2bf(acc2[r]);
                op[(size_t)r * PCOLS + 48] = f2bf(acc3[r]);
            }
        } else {
            float* op = p.QR + (size_t)row0 * 256 + (slice - 16) * H + lo + l15;
#pragma unroll
            for (int r = 0; r < 4; ++r) {
                op[(size_t)r * 256 + 0]  = acc0[r];
                op[(size_t)r * 256 + 16] = acc1[r];
                op[(size_t)r * 256 + 32] = acc2[r];
                op[(size_t)r * 256 + 48] = acc3[r];
            }
        }
        __syncthreads();
    }
}

// ---- fused per-node edge aggregation (CSR) + mean + BN stats --------------
__device__ __forceinline__ void edge_stats_phase(const MP& p, int l, unsigned char* smem)
{
    float* sS = (float*)smem;                  // [4][128]
    float* sQ = sS + 4 * H;                    // [4][128]
    const int tid = threadIdx.x;
    const int sb = tid >> 6;
    const int o2 = tid & 63;
    const int v = blockIdx.x * 4 + sb;
    if (v >= p.N) return;

    const int st = p.offs[v];
    const int deg = p.hist[v];
    float m0 = 0.f, m1 = 0.f;
    for (int k = 0; k < deg; ++k) {
        const int e = p.eord[st + k];
        const int s = p.src[e];
        const float* eap = p.eattr + (size_t)e * EDIM;
        const float4 w0 = *(const float4*)(eap + 0);
        const float4 w1 = *(const float4*)(eap + 4);
        const float4 w2 = *(const float4*)(eap + 8);
        const float4 w3 = *(const float4*)(eap + 12);
        const float w[16] = {w0.x, w0.y, w0.z, w0.w, w1.x, w1.y, w1.z, w1.w,
                             w2.x, w2.y, w2.z, w2.w, w3.x, w3.y, w3.z, w3.w};
        const uint_t* prow = (const uint_t*)(p.Pb + (size_t)s * PCOLS) + o2;
        const float2 q2 = *(const float2*)(p.QR + (size_t)s * 256 + 2 * o2);
        m0 += q2.x;
        m1 += q2.y;
#pragma unroll
        for (int d = 0; d < EDIM; ++d) {
            const uint_t u = prow[(size_t)d * 64];
            m0 = fmaf(w[d], bf_lo(u), m0);
            m1 = fmaf(w[d], bf_hi(u), m1);
        }
    }
    const float rc = 1.0f / (float)(deg > 0 ? deg : 1);
    const float2 rt = *(const float2*)(p.QR + (size_t)v * 256 + H + 2 * o2);
    const float2 cb = *(const float2*)(p.conv_b + (size_t)l * H + 2 * o2);
    const float val0 = m0 * rc + rt.x + cb.x;
    const float val1 = m1 * rc + rt.y + cb.y;
    *(float2*)(p.xnew + (size_t)v * H + 2 * o2) = make_float2(val0, val1);
    sS[sb * H + 2 * o2] = val0; sS[sb * H + 2 * o2 + 1] = val1;
    sQ[sb * H + 2 * o2] = val0 * val0; sQ[sb * H + 2 * o2 + 1] = val1 * val1;
    __syncthreads();
    if (tid < H) {
        const float s4 = sS[0 * H + tid] + sS[1 * H + tid] + sS[2 * H + tid] + sS[3 * H + tid];
        const float q4 = sQ[0 * H + tid] + sQ[1 * H + tid] + sQ[2 * H + tid] + sQ[3 * H + tid];
        atomicAdd(&p.bnS[l * H + tid], s4);
        atomicAdd(&p.bnQ[l * H + tid], q4);
    }
}

// ---- h += relu(bn(xnew)); emit hbf; last layer scatters into gsum ---------
__device__ __forceinline__ void bn_phase(const MP& p, int l)
{
    const int total = p.N * H;
    const float invN = 1.0f / (float)p.N;
    const int last = (l == NLAYER - 1);
    for (int idx = blockIdx.x * NTHR + threadIdx.x; idx < total; idx += NBLK * NTHR) {
        const int c = idx & 127;
        const int v = idx >> 7;
        const float mu = p.bnS[l * H + c] * invN;
        const float var = p.bnQ[l * H + c] * invN - mu * mu;
        const float val = (p.xnew[idx] - mu) * rsqrtf(var + 1e-5f) * p.gamma[l * H + c]
                        + p.beta[l * H + c];
        const float hn = p.h[idx] + fmaxf(val, 0.f);
        p.h[idx] = hn;
        p.hbf[idx] = f2bf(hn);
        if (last) atomicAdd(&p.gsum[p.batch[v] * H + c], hn);
    }
}

__device__ __forceinline__ void classifier_phase(const MP& p)
{
    const int g = blockIdx.x;
    const int j = threadIdx.x;    // < 64
    const float rc = 1.0f / fmaxf(p.cntG[g], 1.0f);
    float acc = p.b1[j];
#pragma unroll 8
    for (int i = 0; i < H; ++i)
        acc = fmaf(p.gsum[g * H + i] * rc, p.W1[i * 64 + j], acc);
    float pv = fmaxf(acc, 0.f) * p.W2[j];
#pragma unroll
    for (int off = 32; off > 0; off >>= 1)
        pv += __shfl_down(pv, off);
    if (j == 0) p.out[g] = pv + p.b2[0];
}

// ---------------------------- the mega kernel ------------------------------
__global__ __launch_bounds__(NTHR, 2) void mega_kernel(MP p)
{
    alignas(16) __shared__ unsigned char smem[64 * 136 * 2 * sizeof(ushort_t)];
    cg::grid_group grid = cg::this_grid();
    const int b = blockIdx.x;
    const int tid = threadIdx.x;

    // phase 0: histograms + weight prep + node embed
    {
        const int t = b * NTHR + tid;
        if (t < p.E) atomicAdd(&p.hist[p.dst[t]], 1);
        if (t < p.N) atomicAdd(&p.cntG[p.batch[t]], 1.f);
    }
    if (b < NLAYER * NSLICE) wprep_phase(p, smem);
    else if (b < NLAYER * NSLICE + 64) embed_phase(p, smem);
    grid.sync();

    // phase 1: scan
    if (b == 0) scan_phase(p, smem);
    grid.sync();

    // phase 2: CSR scatter + layer-0 P-GEMM
    {
        const int e = b * NTHR + tid;
        if (e < p.E) {
            const int d = p.dst[e];
            const int pos = p.offs[d] + atomicAdd(&p.fill[d], 1);
            p.eord[pos] = e;
        }
    }
    mfma_phase(p, 0, smem);

    for (int l = 0; l < NLAYER; ++l) {
        grid.sync();
        edge_stats_phase(p, l, smem);
        grid.sync();
        bn_phase(p, l);
        if (l < NLAYER - 1) {
            grid.sync();
            mfma_phase(p, l + 1, smem);
        }
    }
    grid.sync();

    // final: classifier (one block per graph, wave 0 only)
    if (b < p.G && tid < 64) classifier_phase(p);
}

extern "C" void kernel_launch(void* const* d_in, const int* in_sizes, int n_in,
                              void* d_out, int out_size, void* d_ws, size_t ws_size,
                              hipStream_t stream)
{
    MP p;
    p.x      = (const float*)d_in[0];
    const int* eidx = (const int*)d_in[1];
    p.eattr  = (const float*)d_in[2];
    p.batch  = (const int*)  d_in[3];
    p.node_W = (const float*)d_in[4];
    p.node_b = (const float*)d_in[5];
    p.edge_W = (const float*)d_in[6];
    p.edge_b = (const float*)d_in[7];
    p.root_W = (const float*)d_in[8];
    p.conv_b = (const float*)d_in[9];
    p.gamma  = (const float*)d_in[10];
    p.beta   = (const float*)d_in[11];
    p.W1     = (const float*)d_in[12];
    p.b1     = (const float*)d_in[13];
    p.W2     = (const float*)d_in[14];
    p.b2     = (const float*)d_in[15];
    p.out    = (float*)d_out;

    p.N = in_sizes[0] / 32;   // 2048
    p.E = in_sizes[1] / 2;    // 8192
    p.G = out_size;           // 128
    p.src = eidx;
    p.dst = eidx + p.E;

    const int N = p.N, E = p.E, G = p.G;

    // ---- workspace layout ----
    p.hist = (int*)d_ws;                                  // N
    p.fill = p.hist + N;                                  // N
    p.cntG = (float*)(p.fill + N);                        // G
    p.bnS  = p.cntG + G;                                  // 3*H
    p.bnQ  = p.bnS + NLAYER * H;                          // 3*H
    p.gsum = p.bnQ + NLAYER * H;                          // G*H
    // --- end of zero region ---
    p.offs = (int*)(p.gsum + (size_t)G * H);              // N+16
    p.eord = p.offs + (N + 16);                           // E
    p.h    = (float*)(p.eord + E);                        // N*H
    p.xnew = p.h + (size_t)N * H;                         // N*H
    p.hbf  = (ushort_t*)(p.xnew + (size_t)N * H);         // N*H
    p.Wt   = p.hbf + (size_t)N * H;                       // 3*WCOLS*H
    p.Pb   = p.Wt + (size_t)NLAYER * WCOLS * H;           // N*PCOLS
    p.QR   = (float*)(p.Pb + (size_t)N * PCOLS);          // N*256

    const size_t zbytes = (size_t)(2 * N) * 4
                        + ((size_t)G + 2 * NLAYER * H + (size_t)G * H) * 4;
    hipMemsetAsync(p.hist, 0, zbytes, stream);

    void* args[] = { (void*)&p };
    hipLaunchCooperativeKernel((const void*)mega_kernel, dim3(NBLK), dim3(NTHR),
                               args, 0, stream);
}

// Round 5
// 224.910 us; speedup vs baseline: 3.7626x; 3.7626x over previous
//
#include <hip/hip_runtime.h>
#include <cstddef>
#include <cstdint>

#define H 128
#define EDIM 16
#define NLAYER 3
#define KU 2304              // U columns: 17*128 (16 ea + ones) + 128 (h append)
#define NSLICE 18            // 16 eW + eb + rW

typedef unsigned short ushort_t;
typedef unsigned int uint_t;
typedef __attribute__((ext_vector_type(8))) short bf16x8;
typedef __attribute__((ext_vector_type(4))) float f32x4;

__device__ __forceinline__ ushort_t f2bf(float f) {
    uint_t u = __builtin_bit_cast(uint_t, f);
    u += 0x7fffu + ((u >> 16) & 1u);   // RNE
    return (ushort_t)(u >> 16);
}
__device__ __forceinline__ uint_t pack2(float a, float b) {
    return (uint_t)f2bf(a) | ((uint_t)f2bf(b) << 16);
}

// ===== setup: block 0 = CSR build; 1..54 = weight prep; 55..(54+NBe) = embed;
//       last block = zero accumulators + graph histogram =====
__global__ __launch_bounds__(256) void setup_kernel(
    const int* __restrict__ dst, const int* __restrict__ batch,
    const float* __restrict__ x, const float* __restrict__ node_W,
    const float* __restrict__ node_b,
    const float* __restrict__ eW, const float* __restrict__ eb,
    const float* __restrict__ rW,
    int* __restrict__ offs, int* __restrict__ deg, int* __restrict__ eord,
    float* __restrict__ cntG, float* __restrict__ bnS, float* __restrict__ bnQ,
    float* __restrict__ gsum, float* __restrict__ h, ushort_t* __restrict__ Wt2,
    int E, int N, int G)
{
    alignas(16) __shared__ unsigned char smem[34816];
    const int b = blockIdx.x;
    const int t = threadIdx.x;
    const int NBe = (N / 64) * 2;          // embed blocks (64 for N=2048)

    if (b == 0) {
        // ---- CSR build, single block, LDS-resident ----
        int* sh = (int*)smem;              // [N] histogram / fill  (N<=2048)
        int* part = sh + 2048;             // [256]
        for (int i = t; i < N; i += 256) sh[i] = 0;
        __syncthreads();
        for (int e = t; e < E; e += 256) atomicAdd(&sh[dst[e]], 1);
        __syncthreads();
        // scan (256 threads x 8)
        const int base = t * 8;
        int v[8], loc[8], s = 0;
#pragma unroll
        for (int j = 0; j < 8; ++j) v[j] = (base + j < N) ? sh[base + j] : 0;
#pragma unroll
        for (int j = 0; j < 8; ++j) { loc[j] = s; s += v[j]; }
        part[t] = s;
        __syncthreads();
        for (int off = 1; off < 256; off <<= 1) {
            int xp = (t >= off) ? part[t - off] : 0;
            __syncthreads();
            part[t] += xp;
            __syncthreads();
        }
        const int boff = (t == 0) ? 0 : part[t - 1];
#pragma unroll
        for (int j = 0; j < 8; ++j) {
            if (base + j < N) {
                deg[base + j] = v[j];
                offs[base + j] = boff + loc[j];
            }
        }
        if (t == 255) offs[N] = boff + s;
        __syncthreads();
        // reuse sh as fill cursors
        for (int i = t; i < N; i += 256) sh[i] = offs[i];
        __syncthreads();
        for (int e = t; e < E; e += 256) {
            const int d = dst[e];
            const int pos = atomicAdd(&sh[d], 1);
            eord[pos] = e;
        }
        return;
    }

    if (b <= NLAYER * NSLICE) {
        // ---- weight prep: fp32 slice [k=i][o] -> bf16 Wt2[(l*128+o)*KU + s*128+i] ----
        ushort_t* tile = (ushort_t*)smem;      // [128][136]
        const int bb = b - 1;
        const int l = bb / NSLICE, s = bb % NSLICE;
        const float* S = (s < 16) ? (eW + ((size_t)l * 16 + s) * (H * H))
                       : (s == 16 ? (eb + (size_t)l * H * H)
                                  : (rW + (size_t)l * H * H));
        const int k = t >> 1, o0 = (t & 1) * 64;
#pragma unroll
        for (int j = 0; j < 64; j += 4) {
            float4 v = *(const float4*)&S[(size_t)k * H + o0 + j];
            tile[k * 136 + o0 + j + 0] = f2bf(v.x);
            tile[k * 136 + o0 + j + 1] = f2bf(v.y);
            tile[k * 136 + o0 + j + 2] = f2bf(v.z);
            tile[k * 136 + o0 + j + 3] = f2bf(v.w);
        }
        __syncthreads();
        const int n = t >> 1, k0 = (t & 1) * 64;
        ushort_t* outp = Wt2 + ((size_t)(l * H + n)) * KU + s * H + k0;
#pragma unroll 8
        for (int j = 0; j < 64; ++j) outp[j] = tile[(k0 + j) * 136 + n];
        return;
    }

    if (b <= NLAYER * NSLICE + NBe) {
        // ---- node embed: h = x @ node_W + node_b (fp32, K=32) ----
        float* As = (float*)smem;              // [16][68]
        float* Bs = As + 16 * 68;              // [16][68]
        const int tt = b - (NLAYER * NSLICE + 1);
        const int bm = (tt >> 1) * 64;
        const int bn = (tt & 1) * 64;
        const int tx = t & 15, ty = t >> 4;
        float acc[4][4];
#pragma unroll
        for (int i = 0; i < 4; ++i)
#pragma unroll
            for (int j = 0; j < 4; ++j) acc[i][j] = 0.f;
        const int ka = t & 15, ma = t >> 4;
        const int nb = t & 63, kb = t >> 6;
        for (int k0 = 0; k0 < 32; k0 += 16) {
#pragma unroll
            for (int r = 0; r < 4; ++r)
                As[ka * 68 + ma + 16 * r] = x[(size_t)(bm + ma + 16 * r) * 32 + (k0 + ka)];
#pragma unroll
            for (int r = 0; r < 4; ++r)
                Bs[(kb + 4 * r) * 68 + nb] = node_W[(size_t)(k0 + kb + 4 * r) * H + bn + nb];
            __syncthreads();
#pragma unroll
            for (int kk = 0; kk < 16; ++kk) {
                const float4 a4 = *(const float4*)&As[kk * 68 + ty * 4];
                const float4 b4 = *(const float4*)&Bs[kk * 68 + tx * 4];
                const float a[4] = {a4.x, a4.y, a4.z, a4.w};
                const float bv[4] = {b4.x, b4.y, b4.z, b4.w};
#pragma unroll
                for (int i = 0; i < 4; ++i)
#pragma unroll
                    for (int j = 0; j < 4; ++j)
                        acc[i][j] = fmaf(a[i], bv[j], acc[i][j]);
            }
            __syncthreads();
        }
#pragma unroll
        for (int i = 0; i < 4; ++i) {
            const int row = bm + ty * 4 + i;
            float4 v;
            v.x = acc[i][0] + node_b[bn + tx * 4 + 0];
            v.y = acc[i][1] + node_b[bn + tx * 4 + 1];
            v.z = acc[i][2] + node_b[bn + tx * 4 + 2];
            v.w = acc[i][3] + node_b[bn + tx * 4 + 3];
            *(float4*)&h[(size_t)row * H + bn + tx * 4] = v;
        }
        return;
    }

    // ---- last block: zero accumulators + graph-size histogram ----
    {
        const int zcount = G * H + 2 * NLAYER * H + G;   // gsum, bnS, bnQ, cntG
        for (int i = t; i < zcount; i += 256) {
            if (i < G * H) gsum[i] = 0.f;
            else if (i < G * H + NLAYER * H) bnS[i - G * H] = 0.f;
            else if (i < G * H + 2 * NLAYER * H) bnQ[i - G * H - NLAYER * H] = 0.f;
            else cntG[i - G * H - 2 * NLAYER * H] = 0.f;
        }
        __syncthreads();
        for (int v = t; v < N; v += 256) atomicAdd(&cntG[batch[v]], 1.f);
    }
}

// ===== U-build: Ub[v, d*128+i] = rc * sum_{e in(v)} ea[e,d]*h[src_e,i]
//       (d=16 => weight 1); cols 2176.. = bf16(h[v]) append ==================
__global__ __launch_bounds__(256) void ubuild_kernel(
    const float* __restrict__ h, const float* __restrict__ ea,
    const int* __restrict__ src, const int* __restrict__ offs,
    const int* __restrict__ deg, const int* __restrict__ eord,
    ushort_t* __restrict__ Ub, int N)
{
    const int tid = threadIdx.x;
    const int sb = tid >> 6;
    const int j = tid & 63;                 // channel pair (2j, 2j+1)
    const int v = blockIdx.x * 4 + sb;
    if (v >= N) return;

    float u[17][2];
#pragma unroll
    for (int d = 0; d < 17; ++d) { u[d][0] = 0.f; u[d][1] = 0.f; }

    const int st = offs[v];
    const int dg = deg[v];
    for (int k = 0; k < dg; ++k) {
        const int e = eord[st + k];
        const int s = src[e];
        const float* eap = ea + (size_t)e * EDIM;
        const float4 w0 = *(const float4*)(eap + 0);
        const float4 w1 = *(const float4*)(eap + 4);
        const float4 w2 = *(const float4*)(eap + 8);
        const float4 w3 = *(const float4*)(eap + 12);
        const float w[16] = {w0.x, w0.y, w0.z, w0.w, w1.x, w1.y, w1.z, w1.w,
                             w2.x, w2.y, w2.z, w2.w, w3.x, w3.y, w3.z, w3.w};
        const float2 h2 = *(const float2*)&h[(size_t)s * H + 2 * j];
        u[16][0] += h2.x;
        u[16][1] += h2.y;
#pragma unroll
        for (int d = 0; d < 16; ++d) {
            u[d][0] = fmaf(w[d], h2.x, u[d][0]);
            u[d][1] = fmaf(w[d], h2.y, u[d][1]);
        }
    }
    const float rc = 1.0f / (float)(dg > 0 ? dg : 1);
    uint_t* outp = (uint_t*)(Ub + (size_t)v * KU) + j;
#pragma unroll
    for (int d = 0; d < 17; ++d)
        outp[(size_t)d * 64] = pack2(u[d][0] * rc, u[d][1] * rc);
    const float2 hv = *(const float2*)&h[(size_t)v * H + 2 * j];
    outp[(size_t)17 * 64] = pack2(hv.x, hv.y);
}

// ===== GEMM + fused BN stats: xnew[2048,128] = Ub @ Wt2_l^T ================
// 16-row M-tiles, full K=2304 per block, BN sum/sumsq in epilogue.
__global__ __launch_bounds__(256) void gemm_stats(
    const ushort_t* __restrict__ Ub, const ushort_t* __restrict__ Wt2l,
    float* __restrict__ xnew, float* __restrict__ bnS, float* __restrict__ bnQ)
{
    __shared__ ushort_t As[16][136];
    __shared__ ushort_t Bs[128][136];
    const int tid = threadIdx.x;
    const int m0 = blockIdx.x * 16;
    const int wave = tid >> 6, lane = tid & 63;
    const int l15 = lane & 15, quad = lane >> 4;

    f32x4 acc0 = {0.f, 0.f, 0.f, 0.f};
    f32x4 acc1 = {0.f, 0.f, 0.f, 0.f};

    for (int c = 0; c < KU / 128; ++c) {
        {
            const int row = tid >> 4, pos = (tid & 15) * 8;
            *(uint4*)&As[row][pos] =
                *(const uint4*)&Ub[(size_t)(m0 + row) * KU + c * 128 + pos];
        }
#pragma unroll
        for (int r = 0; r < 8; ++r) {
            const int idx = tid + r * 256;
            const int row = idx >> 4, pos = (idx & 15) * 8;
            *(uint4*)&Bs[row][pos] =
                *(const uint4*)&Wt2l[(size_t)row * KU + c * 128 + pos];
        }
        __syncthreads();
#pragma unroll
        for (int ks = 0; ks < 4; ++ks) {
            const int k = ks * 32 + quad * 8;
            bf16x8 a  = *(const bf16x8*)&As[l15][k];
            bf16x8 b0 = *(const bf16x8*)&Bs[wave * 16 + l15][k];
            bf16x8 b1 = *(const bf16x8*)&Bs[(wave + 4) * 16 + l15][k];
            acc0 = __builtin_amdgcn_mfma_f32_16x16x32_bf16(a, b0, acc0, 0, 0, 0);
            acc1 = __builtin_amdgcn_mfma_f32_16x16x32_bf16(a, b1, acc1, 0, 0, 0);
        }
        __syncthreads();
    }

    // epilogue: write xnew + per-column sum/sumsq
    float s0 = 0.f, q0 = 0.f, s1 = 0.f, q1 = 0.f;
#pragma unroll
    for (int r = 0; r < 4; ++r) {
        const int row = m0 + quad * 4 + r;
        const float v0 = acc0[r];
        const float v1 = acc1[r];
        xnew[(size_t)row * H + wave * 16 + l15] = v0;
        xnew[(size_t)row * H + (wave + 4) * 16 + l15] = v1;
        s0 += v0; q0 += v0 * v0;
        s1 += v1; q1 += v1 * v1;
    }
    s0 += __shfl_down(s0, 32); s0 += __shfl_down(s0, 16);
    q0 += __shfl_down(q0, 32); q0 += __shfl_down(q0, 16);
    s1 += __shfl_down(s1, 32); s1 += __shfl_down(s1, 16);
    q1 += __shfl_down(q1, 32); q1 += __shfl_down(q1, 16);
    if (quad == 0) {
        atomicAdd(&bnS[wave * 16 + l15], s0);
        atomicAdd(&bnQ[wave * 16 + l15], q0);
        atomicAdd(&bnS[(wave + 4) * 16 + l15], s1);
        atomicAdd(&bnQ[(wave + 4) * 16 + l15], q1);
    }
}

// ===== h += relu(bn(xnew)); last layer scatters into gsum ==================
// (conv_bias omitted: additive per-channel constants cancel under BatchNorm)
__global__ __launch_bounds__(256) void bn_apply(
    float* __restrict__ h, const float* __restrict__ xnew,
    const float* __restrict__ bnS, const float* __restrict__ bnQ,
    const float* __restrict__ gamma, const float* __restrict__ beta,
    const int* __restrict__ batch, float* __restrict__ gsum, int N, int last)
{
    const int idx = blockIdx.x * 256 + threadIdx.x;
    const int c = idx & 127;
    const int v = idx >> 7;
    const float invN = 1.0f / (float)N;
    const float mu = bnS[c] * invN;
    const float var = bnQ[c] * invN - mu * mu;
    const float val = (xnew[idx] - mu) * rsqrtf(var + 1e-5f) * gamma[c] + beta[c];
    const float hn = h[idx] + fmaxf(val, 0.f);
    h[idx] = hn;
    if (last) atomicAdd(&gsum[batch[v] * H + c], hn);
}

__global__ void classifier_kernel(
    const float* __restrict__ gsum, const float* __restrict__ cntG,
    const float* __restrict__ W1, const float* __restrict__ b1,
    const float* __restrict__ W2, const float* __restrict__ b2,
    float* __restrict__ out)
{
    const int g = blockIdx.x;
    const int j = threadIdx.x;  // 64
    const float rc = 1.0f / fmaxf(cntG[g], 1.0f);
    float acc = b1[j];
#pragma unroll 8
    for (int i = 0; i < H; ++i)
        acc = fmaf(gsum[g * H + i] * rc, W1[i * 64 + j], acc);
    float pv = fmaxf(acc, 0.f) * W2[j];
#pragma unroll
    for (int off = 32; off > 0; off >>= 1)
        pv += __shfl_down(pv, off);
    if (j == 0) out[g] = pv + b2[0];
}

extern "C" void kernel_launch(void* const* d_in, const int* in_sizes, int n_in,
                              void* d_out, int out_size, void* d_ws, size_t ws_size,
                              hipStream_t stream)
{
    const float* x      = (const float*)d_in[0];
    const int*   eidx   = (const int*)  d_in[1];
    const float* eattr  = (const float*)d_in[2];
    const int*   batch  = (const int*)  d_in[3];
    const float* node_W = (const float*)d_in[4];
    const float* node_b = (const float*)d_in[5];
    const float* edge_W = (const float*)d_in[6];
    const float* edge_b = (const float*)d_in[7];
    const float* root_W = (const float*)d_in[8];
    const float* gamma  = (const float*)d_in[10];
    const float* beta   = (const float*)d_in[11];
    const float* W1     = (const float*)d_in[12];
    const float* b1     = (const float*)d_in[13];
    const float* W2     = (const float*)d_in[14];
    const float* b2     = (const float*)d_in[15];
    float* out = (float*)d_out;

    const int N = in_sizes[0] / 32;   // 2048
    const int E = in_sizes[1] / 2;    // 8192
    const int G = out_size;           // 128

    const int* src = eidx;
    const int* dst = eidx + E;

    // ---- workspace layout ----
    int* offs  = (int*)d_ws;                               // N+16
    int* deg   = offs + (N + 16);                          // N
    int* eord  = deg + N;                                  // E
    float* cntG = (float*)(eord + E);                      // G
    float* bnS  = cntG + G;                                // 3*H
    float* bnQ  = bnS + NLAYER * H;                        // 3*H
    float* gsum = bnQ + NLAYER * H;                        // G*H
    float* h    = gsum + (size_t)G * H;                    // N*H
    float* xnew = h + (size_t)N * H;                       // N*H
    ushort_t* Wt2 = (ushort_t*)(xnew + (size_t)N * H);     // 3*128*KU
    ushort_t* Ub  = Wt2 + (size_t)NLAYER * H * KU;         // N*KU

    const int NBe = (N / 64) * 2;
    const int nsetup = 1 + NLAYER * NSLICE + NBe + 1;      // 120 blocks

    setup_kernel<<<nsetup, 256, 0, stream>>>(
        dst, batch, x, node_W, node_b, edge_W, edge_b, root_W,
        offs, deg, eord, cntG, bnS, bnQ, gsum, h, Wt2, E, N, G);

    for (int l = 0; l < NLAYER; ++l) {
        ubuild_kernel<<<N / 4, 256, 0, stream>>>(
            h, eattr, src, offs, deg, eord, Ub, N);
        gemm_stats<<<N / 16, 256, 0, stream>>>(
            Ub, Wt2 + (size_t)l * H * KU, xnew, bnS + l * H, bnQ + l * H);
        bn_apply<<<(N * H) / 256, 256, 0, stream>>>(
            h, xnew, bnS + l * H, bnQ + l * H,
            gamma + (size_t)l * H, beta + (size_t)l * H,
            batch, gsum, N, l == NLAYER - 1);
    }

    classifier_kernel<<<G, 64, 0, stream>>>(gsum, cntG, W1, b1, W2, b2, out);
}

// Round 6
// 206.467 us; speedup vs baseline: 4.0987x; 1.0893x over previous
//
#include <hip/hip_runtime.h>
#include <cstddef>
#include <cstdint>

#define H 128
#define EDIM 16
#define NLAYER 3
#define KU 2304              // 17*128 (16 ea slices + ones) + 128 (h append)
#define NSLICE 18
#define ASTRIDE 2312         // U row stride in ushorts (2304 + 8 pad)

typedef unsigned short ushort_t;
typedef unsigned int uint_t;
typedef __attribute__((ext_vector_type(8))) short bf16x8;
typedef __attribute__((ext_vector_type(4))) float f32x4;

__device__ __forceinline__ ushort_t f2bf(float f) {
    uint_t u = __builtin_bit_cast(uint_t, f);
    u += 0x7fffu + ((u >> 16) & 1u);   // RNE
    return (ushort_t)(u >> 16);
}
__device__ __forceinline__ uint_t pack2(float a, float b) {
    return (uint_t)f2bf(a) | ((uint_t)f2bf(b) << 16);
}

// ===== setup (1024-thread blocks): 0=CSR; 1..54=weight prep; 55..70=embed;
//       71=zero accumulators + graph histogram ==============================
__global__ __launch_bounds__(1024) void setup_kernel(
    const int* __restrict__ dst, const int* __restrict__ batch,
    const float* __restrict__ x, const float* __restrict__ node_W,
    const float* __restrict__ node_b,
    const float* __restrict__ eW, const float* __restrict__ eb,
    const float* __restrict__ rW,
    int* __restrict__ offs, int* __restrict__ deg, int* __restrict__ eord,
    float* __restrict__ cntG, float* __restrict__ bnS, float* __restrict__ bnQ,
    float* __restrict__ gsum, float* __restrict__ h, ushort_t* __restrict__ Wt2,
    int E, int N, int G)
{
    alignas(16) __shared__ unsigned char smem[36864];
    const int b = blockIdx.x;
    const int t = threadIdx.x;

    if (b == 0) {
        // ---- CSR build, one block, 1024 threads, LDS-resident ----
        int* sh = (int*)smem;              // [2048] histogram / cursors
        int* part = sh + 2048;             // [1024]
        for (int i = t; i < N; i += 1024) sh[i] = 0;
        __syncthreads();
        for (int e = t; e < E; e += 1024) atomicAdd(&sh[dst[e]], 1);
        __syncthreads();
        // scan: thread t owns elements 2t, 2t+1
        const int v0 = (2 * t < N) ? sh[2 * t] : 0;
        const int v1 = (2 * t + 1 < N) ? sh[2 * t + 1] : 0;
        part[t] = v0 + v1;
        __syncthreads();
        for (int off = 1; off < 1024; off <<= 1) {
            int xp = (t >= off) ? part[t - off] : 0;
            __syncthreads();
            part[t] += xp;
            __syncthreads();
        }
        const int boff = (t == 0) ? 0 : part[t - 1];
        if (2 * t < N) { deg[2 * t] = v0; offs[2 * t] = boff; }
        if (2 * t + 1 < N) { deg[2 * t + 1] = v1; offs[2 * t + 1] = boff + v0; }
        if (t == 1023) offs[N] = part[1023];
        __syncthreads();
        // cursors (recomputed locally, no global round-trip)
        if (2 * t < N) sh[2 * t] = boff;
        if (2 * t + 1 < N) sh[2 * t + 1] = boff + v0;
        __syncthreads();
        for (int e = t; e < E; e += 1024) {
            const int d = dst[e];
            const int pos = atomicAdd(&sh[d], 1);
            eord[pos] = e;
        }
        return;
    }

    if (b <= NLAYER * NSLICE) {
        // ---- weight prep: fp32 slice [k=i][o] -> bf16 Wt2[(l*128+o)*KU + s*128+i]
        ushort_t* tile = (ushort_t*)smem;      // [128][136]
        const int bb = b - 1;
        const int l = bb / NSLICE, s = bb % NSLICE;
        const float* S = (s < 16) ? (eW + ((size_t)l * 16 + s) * (H * H))
                       : (s == 16 ? (eb + (size_t)l * H * H)
                                  : (rW + (size_t)l * H * H));
        const int k = t >> 3, o0 = (t & 7) * 16;
#pragma unroll
        for (int j = 0; j < 16; j += 4) {
            float4 v = *(const float4*)&S[(size_t)k * H + o0 + j];
            tile[k * 136 + o0 + j + 0] = f2bf(v.x);
            tile[k * 136 + o0 + j + 1] = f2bf(v.y);
            tile[k * 136 + o0 + j + 2] = f2bf(v.z);
            tile[k * 136 + o0 + j + 3] = f2bf(v.w);
        }
        __syncthreads();
        const int n = t >> 3, k0 = (t & 7) * 16;
        ushort_t* outp = Wt2 + ((size_t)(l * H + n)) * KU + s * H + k0;
#pragma unroll
        for (int j = 0; j < 16; ++j) outp[j] = tile[(k0 + j) * 136 + n];
        return;
    }

    if (b <= NLAYER * NSLICE + 16) {
        // ---- node embed: h = x @ node_W + node_b (fp32, K=32) ----
        // 4 subgroups of 256 threads, each one 64x64 tile
        const int sub = t >> 8;
        const int st = t & 255;
        float* As = (float*)(smem + sub * 8704);       // [16][68]
        float* Bs = As + 16 * 68;                      // [16][68]
        const int tt = (b - (NLAYER * NSLICE + 1)) * 4 + sub;
        const int bm = (tt >> 1) * 64;
        const int bn = (tt & 1) * 64;
        const int tx = st & 15, ty = st >> 4;
        float acc[4][4];
#pragma unroll
        for (int i = 0; i < 4; ++i)
#pragma unroll
            for (int j = 0; j < 4; ++j) acc[i][j] = 0.f;
        const int ka = st & 15, ma = st >> 4;
        const int nb = st & 63, kb = st >> 6;
        for (int k0 = 0; k0 < 32; k0 += 16) {
#pragma unroll
            for (int r = 0; r < 4; ++r)
                As[ka * 68 + ma + 16 * r] = x[(size_t)(bm + ma + 16 * r) * 32 + (k0 + ka)];
#pragma unroll
            for (int r = 0; r < 4; ++r)
                Bs[(kb + 4 * r) * 68 + nb] = node_W[(size_t)(k0 + kb + 4 * r) * H + bn + nb];
            __syncthreads();
#pragma unroll
            for (int kk = 0; kk < 16; ++kk) {
                const float4 a4 = *(const float4*)&As[kk * 68 + ty * 4];
                const float4 b4 = *(const float4*)&Bs[kk * 68 + tx * 4];
                const float a[4] = {a4.x, a4.y, a4.z, a4.w};
                const float bv[4] = {b4.x, b4.y, b4.z, b4.w};
#pragma unroll
                for (int i = 0; i < 4; ++i)
#pragma unroll
                    for (int j = 0; j < 4; ++j)
                        acc[i][j] = fmaf(a[i], bv[j], acc[i][j]);
            }
            __syncthreads();
        }
#pragma unroll
        for (int i = 0; i < 4; ++i) {
            const int row = bm + ty * 4 + i;
            float4 v;
            v.x = acc[i][0] + node_b[bn + tx * 4 + 0];
            v.y = acc[i][1] + node_b[bn + tx * 4 + 1];
            v.z = acc[i][2] + node_b[bn + tx * 4 + 2];
            v.w = acc[i][3] + node_b[bn + tx * 4 + 3];
            *(float4*)&h[(size_t)row * H + bn + tx * 4] = v;
        }
        return;
    }

    // ---- last block: zero accumulators + graph-size histogram ----
    {
        const int zcount = G * H + 2 * NLAYER * H + G;
        for (int i = t; i < zcount; i += 1024) {
            if (i < G * H) gsum[i] = 0.f;
            else if (i < G * H + NLAYER * H) bnS[i - G * H] = 0.f;
            else if (i < G * H + 2 * NLAYER * H) bnQ[i - G * H - NLAYER * H] = 0.f;
            else cntG[i - G * H - 2 * NLAYER * H] = 0.f;
        }
        __syncthreads();
        for (int v = t; v < N; v += 1024) atomicAdd(&cntG[batch[v]], 1.f);
    }
}

// ===== fused per-layer: build 8 U-rows in LDS, then MFMA GEMM vs Wt2_l =====
// 256 blocks x 512 threads. Wave w builds node v = blockIdx.x*8 + w.
// GEMM: xnew[8,128] tile; A rows via l15&7 duplication; BN stats in epilogue.
__global__ __launch_bounds__(512, 4) void ubuild_gemm(
    const float* __restrict__ h, const float* __restrict__ ea,
    const int* __restrict__ src, const int* __restrict__ offs,
    const int* __restrict__ deg, const int* __restrict__ eord,
    const ushort_t* __restrict__ Wt2l,
    float* __restrict__ xnew, float* __restrict__ bnS, float* __restrict__ bnQ)
{
    __shared__ ushort_t As8[8 * ASTRIDE];      // 36992 B
    __shared__ ushort_t Bs[128][136];          // 34816 B
    const int tid = threadIdx.x;
    const int w = tid >> 6;                    // wave 0..7
    const int lane = tid & 63;
    const int m0 = blockIdx.x * 8;

    // ---- build phase: wave w builds U row w (node v = m0 + w) ----
    {
        const int v = m0 + w;
        const int j = lane;                    // channel pair (2j, 2j+1)
        float u[17][2];
#pragma unroll
        for (int d = 0; d < 17; ++d) { u[d][0] = 0.f; u[d][1] = 0.f; }
        const int st = offs[v];
        const int dg = deg[v];
        for (int k = 0; k < dg; ++k) {
            const int e = eord[st + k];
            const int s = src[e];
            const float* eap = ea + (size_t)e * EDIM;
            const float4 w0 = *(const float4*)(eap + 0);
            const float4 w1 = *(const float4*)(eap + 4);
            const float4 w2 = *(const float4*)(eap + 8);
            const float4 w3 = *(const float4*)(eap + 12);
            const float wv[16] = {w0.x, w0.y, w0.z, w0.w, w1.x, w1.y, w1.z, w1.w,
                                  w2.x, w2.y, w2.z, w2.w, w3.x, w3.y, w3.z, w3.w};
            const float2 h2 = *(const float2*)&h[(size_t)s * H + 2 * j];
            u[16][0] += h2.x;
            u[16][1] += h2.y;
#pragma unroll
            for (int d = 0; d < 16; ++d) {
                u[d][0] = fmaf(wv[d], h2.x, u[d][0]);
                u[d][1] = fmaf(wv[d], h2.y, u[d][1]);
            }
        }
        const float rc = 1.0f / (float)(dg > 0 ? dg : 1);
        uint_t* urow = (uint_t*)&As8[w * ASTRIDE];
#pragma unroll
        for (int d = 0; d < 17; ++d)
            urow[j + d * 64] = pack2(u[d][0] * rc, u[d][1] * rc);
        const float2 hv = *(const float2*)&h[(size_t)v * H + 2 * j];
        urow[j + 17 * 64] = pack2(hv.x, hv.y);
    }

    // ---- GEMM phase ----
    const int l15 = lane & 15, quad = lane >> 4;
    f32x4 acc = {0.f, 0.f, 0.f, 0.f};
    const ushort_t* arow = &As8[(l15 & 7) * ASTRIDE];

    for (int c = 0; c < KU / 128; ++c) {
        // stage B chunk: rows = out-cols 0..127, k-cols c*128..c*128+127
#pragma unroll
        for (int r = 0; r < 4; ++r) {
            const int idx = tid + r * 512;
            const int row = idx >> 4, pos = (idx & 15) * 8;
            *(uint4*)&Bs[row][pos] =
                *(const uint4*)&Wt2l[(size_t)row * KU + c * 128 + pos];
        }
        __syncthreads();
#pragma unroll
        for (int ks = 0; ks < 4; ++ks) {
            const int k = ks * 32 + quad * 8;
            bf16x8 a = *(const bf16x8*)&arow[c * 128 + k];
            bf16x8 b = *(const bf16x8*)&Bs[w * 16 + l15][k];
            acc = __builtin_amdgcn_mfma_f32_16x16x32_bf16(a, b, acc, 0, 0, 0);
        }
        __syncthreads();
    }

    // ---- epilogue: rows m = quad*4+r valid for quad<2 (m<8); col = w*16+l15
    const int col = w * 16 + l15;
    float s = 0.f, q = 0.f;
    if (quad < 2) {
#pragma unroll
        for (int r = 0; r < 4; ++r) {
            const int m = quad * 4 + r;
            const float val = acc[r];
            xnew[(size_t)(m0 + m) * H + col] = val;
            s += val;
            q += val * val;
        }
    }
    s += __shfl_down(s, 16);
    q += __shfl_down(q, 16);
    if (lane < 16) {
        atomicAdd(&bnS[col], s);
        atomicAdd(&bnQ[col], q);
    }
}

// ===== h += relu(bn(xnew)); last layer scatters into gsum ==================
// (conv_bias omitted: additive per-channel constants cancel under BatchNorm)
__global__ __launch_bounds__(256) void bn_apply(
    float* __restrict__ h, const float* __restrict__ xnew,
    const float* __restrict__ bnS, const float* __restrict__ bnQ,
    const float* __restrict__ gamma, const float* __restrict__ beta,
    const int* __restrict__ batch, float* __restrict__ gsum, int N, int last)
{
    const int idx = blockIdx.x * 256 + threadIdx.x;
    const int c = idx & 127;
    const int v = idx >> 7;
    const float invN = 1.0f / (float)N;
    const float mu = bnS[c] * invN;
    const float var = bnQ[c] * invN - mu * mu;
    const float val = (xnew[idx] - mu) * rsqrtf(var + 1e-5f) * gamma[c] + beta[c];
    const float hn = h[idx] + fmaxf(val, 0.f);
    h[idx] = hn;
    if (last) atomicAdd(&gsum[batch[v] * H + c], hn);
}

__global__ void classifier_kernel(
    const float* __restrict__ gsum, const float* __restrict__ cntG,
    const float* __restrict__ W1, const float* __restrict__ b1,
    const float* __restrict__ W2, const float* __restrict__ b2,
    float* __restrict__ out)
{
    const int g = blockIdx.x;
    const int j = threadIdx.x;  // 64
    const float rc = 1.0f / fmaxf(cntG[g], 1.0f);
    float acc = b1[j];
#pragma unroll 8
    for (int i = 0; i < H; ++i)
        acc = fmaf(gsum[g * H + i] * rc, W1[i * 64 + j], acc);
    float pv = fmaxf(acc, 0.f) * W2[j];
#pragma unroll
    for (int off = 32; off > 0; off >>= 1)
        pv += __shfl_down(pv, off);
    if (j == 0) out[g] = pv + b2[0];
}

extern "C" void kernel_launch(void* const* d_in, const int* in_sizes, int n_in,
                              void* d_out, int out_size, void* d_ws, size_t ws_size,
                              hipStream_t stream)
{
    const float* x      = (const float*)d_in[0];
    const int*   eidx   = (const int*)  d_in[1];
    const float* eattr  = (const float*)d_in[2];
    const int*   batch  = (const int*)  d_in[3];
    const float* node_W = (const float*)d_in[4];
    const float* node_b = (const float*)d_in[5];
    const float* edge_W = (const float*)d_in[6];
    const float* edge_b = (const float*)d_in[7];
    const float* root_W = (const float*)d_in[8];
    const float* gamma  = (const float*)d_in[10];
    const float* beta   = (const float*)d_in[11];
    const float* W1     = (const float*)d_in[12];
    const float* b1     = (const float*)d_in[13];
    const float* W2     = (const float*)d_in[14];
    const float* b2     = (const float*)d_in[15];
    float* out = (float*)d_out;

    const int N = in_sizes[0] / 32;   // 2048
    const int E = in_sizes[1] / 2;    // 8192
    const int G = out_size;           // 128

    const int* src = eidx;
    const int* dst = eidx + E;

    // ---- workspace layout ----
    int* offs  = (int*)d_ws;                               // N+16
    int* deg   = offs + (N + 16);                          // N
    int* eord  = deg + N;                                  // E
    float* cntG = (float*)(eord + E);                      // G
    float* bnS  = cntG + G;                                // 3*H
    float* bnQ  = bnS + NLAYER * H;                        // 3*H
    float* gsum = bnQ + NLAYER * H;                        // G*H
    float* h    = gsum + (size_t)G * H;                    // N*H
    float* xnew = h + (size_t)N * H;                       // N*H
    ushort_t* Wt2 = (ushort_t*)(xnew + (size_t)N * H);     // 3*128*KU

    const int nsetup = 1 + NLAYER * NSLICE + 16 + 1;       // 72 blocks

    setup_kernel<<<nsetup, 1024, 0, stream>>>(
        dst, batch, x, node_W, node_b, edge_W, edge_b, root_W,
        offs, deg, eord, cntG, bnS, bnQ, gsum, h, Wt2, E, N, G);

    for (int l = 0; l < NLAYER; ++l) {
        ubuild_gemm<<<N / 8, 512, 0, stream>>>(
            h, eattr, src, offs, deg, eord,
            Wt2 + (size_t)l * H * KU,
            xnew, bnS + l * H, bnQ + l * H);
        bn_apply<<<(N * H) / 256, 256, 0, stream>>>(
            h, xnew, bnS + l * H, bnQ + l * H,
            gamma + (size_t)l * H, beta + (size_t)l * H,
            batch, gsum, N, l == NLAYER - 1);
    }

    classifier_kernel<<<G, 64, 0, stream>>>(gsum, cntG, W1, b1, W2, b2, out);
}